// Round 8
// baseline (839.082 us; speedup 1.0000x reference)
//
#include <hip/hip_runtime.h>
#include <math.h>

#define N    257     // state dim
#define AP   258     // doubles per A row (cols 0..256 = S, col 257 = rhs)
#define MM   128     // rotation pairs
#define LL   512     // seq length
#define BB   4       // batch
#define NB   32      // panel width

// ws byte layout:
#define A_BYTE    0         // double[257*258] = 530448
#define W0_BYTE   530448    // float[257]
#define CXY_BYTE  531488    // float[4096]
#define U12_BYTE  613696    // double[32*226] = 57856
#define INVU_BYTE 671552    // double[32*32]  = 8192
// total ~680 KB (ws >= 1.26 MB proven by earlier rounds)

// ---------------------------------------------------------------------------
// prefix sums of x[b,:,comp]: theta[b,l,m] = cx[b,l]*om0[m] + cy[b,l]*om1[m]
// ---------------------------------------------------------------------------
__global__ __launch_bounds__(512) void scan_kernel(const float* __restrict__ x,
                                                   void* __restrict__ wsv) {
  const int tid  = threadIdx.x;
  const int wave = tid >> 6, lane = tid & 63;
  const int b    = wave >> 1, comp = wave & 1;

  const float* xp = x + ((size_t)b * LL) * 2 + comp;
  double loc[8];
  double run = 0.0;
  #pragma unroll
  for (int e = 0; e < 8; ++e) {
    run += (double)xp[(lane * 8 + e) * 2];
    loc[e] = run;
  }
  double tot = run;
  #pragma unroll
  for (int off = 1; off < 64; off <<= 1) {
    const double o = __shfl_up(tot, off);
    if (lane >= off) tot += o;
  }
  const double excl = tot - run;
  float* cp = (float*)((char*)wsv + CXY_BYTE) + ((size_t)b * LL) * 2 + comp;
  #pragma unroll
  for (int e = 0; e < 8; ++e)
    cp[(lane * 8 + e) * 2] = (float)(excl + loc[e]);
}

// ---------------------------------------------------------------------------
// stage A = [S | z0] in fp64, grid-wide
// ---------------------------------------------------------------------------
__global__ __launch_bounds__(256) void stage_kernel(const float* __restrict__ S,
                                                    const float* __restrict__ z0,
                                                    void* __restrict__ wsv) {
  double* A = (double*)((char*)wsv + A_BYTE);
  const int idx = blockIdx.x * 256 + threadIdx.x;
  if (idx < N * N) {
    const int i = idx / N, j = idx - i * N;
    A[i * AP + j] = (double)S[idx];
  } else {
    const int r = idx - N * N;
    if (r < N) A[r * AP + N] = (double)z0[r];
  }
}

// ---------------------------------------------------------------------------
// diag kernel (1 block, 256 thr): ONLY the irreducible 32x32 sequential core.
//  1. unpivoted LU of the 32x32 diagonal block (32 short LDS steps)
//  2. invL11 / invU11 by 32 parallel per-column substitutions
//  3. U12 = invL11 * A12 as a dense product (no serial chains) -> A + U12w
//  4. exports invU11 for the grid update kernel; U11+L -> A for finish
// ---------------------------------------------------------------------------
__global__ __launch_bounds__(256) void diag_kernel(void* __restrict__ wsv, int k0) {
  __shared__ double B [NB][NB + 1];
  __shared__ double iL[NB][NB + 1];
  __shared__ double iU[NB][NB + 1];
  __shared__ double A12s[NB][227];
  double* A    = (double*)((char*)wsv + A_BYTE);
  double* U12w = (double*)((char*)wsv + U12_BYTE);
  double* invU = (double*)((char*)wsv + INVU_BYTE);
  const int tid = threadIdx.x;
  const int ct  = k0 + NB;
  const int tc2 = 258 - ct;            // trailing cols incl rhs

  // load diag block + stage pivot rows' trailing block (coalesced)
  for (int idx = tid; idx < NB * NB; idx += 256) {
    const int i = idx >> 5, c = idx & 31;
    B[i][c] = A[(k0 + i) * AP + k0 + c];
  }
  for (int idx = tid; idx < NB * tc2; idx += 256) {
    const int t = idx / tc2, c = idx - t * tc2;
    A12s[t][c] = A[(k0 + t) * AP + ct + c];
  }
  __syncthreads();

  // 1. unpivoted LU (row-per-thread, one barrier per step)
  for (int j = 0; j < NB; ++j) {
    if (tid > j && tid < NB) {
      const double m = B[tid][j] / B[j][j];
      B[tid][j] = m;
      #pragma unroll 4
      for (int c = j + 1; c < NB; ++c) B[tid][c] -= m * B[j][c];
    }
    __syncthreads();
  }

  // U11 (+L mults) -> A: finish_kernel needs the U11 upper triangle
  for (int idx = tid; idx < NB * NB; idx += 256) {
    const int i = idx >> 5, c = idx & 31;
    A[(k0 + i) * AP + k0 + c] = B[i][c];
  }

  // 2. triangular inverses, one column per thread (col-private chains)
  if (tid < NB) {
    const int e = tid;               // invL11 column e (unit lower)
    for (int i = 0; i < NB; ++i) {
      double v = (i == e) ? 1.0 : 0.0;
      for (int t = e; t < i; ++t) v -= B[i][t] * iL[t][e];
      iL[i][e] = (i >= e) ? v : 0.0;
    }
  } else if (tid < 2 * NB) {
    const int e = tid - NB;          // invU11 column e
    for (int i = NB - 1; i >= 0; --i) {
      double v = (i == e) ? 1.0 : 0.0;
      for (int t = i + 1; t <= e; ++t) v -= B[i][t] * iU[t][e];
      iU[i][e] = (i <= e) ? v / B[i][i] : 0.0;
    }
  }
  __syncthreads();

  // 4. export invU11
  for (int idx = tid; idx < NB * NB; idx += 256)
    invU[idx] = iU[idx >> 5][idx & 31];

  // 3. U12 = invL11 * A12  (dense; register acc, broadcast iL reads)
  for (int c = tid; c < tc2; c += 256) {
    for (int i = 0; i < NB; ++i) {
      double v = A12s[i][c];                       // iL[i][i] = 1
      for (int t = 0; t < i; ++t) v += iL[i][t] * A12s[t][c];
      A[(k0 + i) * AP + ct + c] = v;               // pivot rows' trailing
      U12w[i * 226 + c] = v;                       // compact for updates
    }
  }
}

// ---------------------------------------------------------------------------
// panel update (grid-parallel): for non-pivot rows R = [0,k0) U [ct,N):
//   Pl = A[R, panel] * invU11        (the L21 / M01 multipliers)
//   A[R, cols] -= Pl * U12w[:, cols] (rank-32 Jordan update, incl rhs)
// ---------------------------------------------------------------------------
__global__ __launch_bounds__(256) void panel_update_kernel(void* __restrict__ wsv,
                                                           int k0, int tc2) {
  __shared__ double Apan[NB][NB + 1];
  __shared__ double iU [NB][NB + 1];
  __shared__ double Pl [NB][NB + 1];
  __shared__ __align__(16) double Ul[NB][66];
  double* A = (double*)((char*)wsv + A_BYTE);
  const double* U12w = (const double*)((const char*)wsv + U12_BYTE);
  const double* invU = (const double*)((const char*)wsv + INVU_BYTE);
  const int tid = threadIdx.x;
  const int ct  = k0 + NB;
  const int rb0 = blockIdx.x * 32;
  const int c0  = blockIdx.y * 64;

  for (int idx = tid; idx < NB * NB; idx += 256) {
    const int i = idx >> 5, c = idx & 31;
    const int rb = rb0 + i;
    const int gr = (rb < k0) ? rb : rb + NB;
    Apan[i][c] = (rb < 225) ? A[gr * AP + k0 + c] : 0.0;
    iU[i][c]   = invU[idx];
  }
  for (int idx = tid; idx < NB * 64; idx += 256) {
    const int t = idx >> 6, c = idx & 63;
    Ul[t][c] = (c0 + c < tc2) ? U12w[t * 226 + c0 + c] : 0.0;
  }
  __syncthreads();

  // Pl = Apan * invU11
  {
    const int r = tid & 31, cg = (tid >> 5) * 4;
    double a0 = 0, a1 = 0, a2 = 0, a3 = 0;
    #pragma unroll 8
    for (int t = 0; t < NB; ++t) {
      const double av = Apan[r][t];
      a0 += av * iU[t][cg + 0];
      a1 += av * iU[t][cg + 1];
      a2 += av * iU[t][cg + 2];
      a3 += av * iU[t][cg + 3];
    }
    Pl[r][cg + 0] = a0; Pl[r][cg + 1] = a1;
    Pl[r][cg + 2] = a2; Pl[r][cg + 3] = a3;
  }
  __syncthreads();

  // rank-32 update, 2x4 per thread
  const int tr  = tid >> 4;
  const int tcx = (tid & 15) * 4;
  double acc[2][4];
  #pragma unroll
  for (int rr = 0; rr < 2; ++rr) {
    const int rb = rb0 + tr * 2 + rr;
    const int gr = (rb < k0) ? rb : rb + NB;
    #pragma unroll
    for (int c = 0; c < 4; ++c)
      acc[rr][c] = (rb < 225 && (c0 + tcx + c) < tc2)
                 ? A[gr * AP + ct + c0 + tcx + c] : 0.0;
  }
  #pragma unroll
  for (int t = 0; t < NB; ++t) {
    const double p0 = Pl[tr * 2][t], p1 = Pl[tr * 2 + 1][t];
    const double2 u0 = *(const double2*)&Ul[t][tcx];
    const double2 u1 = *(const double2*)&Ul[t][tcx + 2];
    acc[0][0] -= p0 * u0.x; acc[0][1] -= p0 * u0.y;
    acc[0][2] -= p0 * u1.x; acc[0][3] -= p0 * u1.y;
    acc[1][0] -= p1 * u0.x; acc[1][1] -= p1 * u0.y;
    acc[1][2] -= p1 * u1.x; acc[1][3] -= p1 * u1.y;
  }
  #pragma unroll
  for (int rr = 0; rr < 2; ++rr) {
    const int rb = rb0 + tr * 2 + rr;
    const int gr = (rb < k0) ? rb : rb + NB;
    #pragma unroll
    for (int c = 0; c < 4; ++c)
      if (rb < 225 && (c0 + tcx + c) < tc2)
        A[gr * AP + ct + c0 + tcx + c] = acc[rr][c];
  }
}

// ---------------------------------------------------------------------------
// finish: x256 division, then 8 independent per-panel 32-step back-substs
// ---------------------------------------------------------------------------
__global__ __launch_bounds__(256) void finish_kernel(void* __restrict__ wsv) {
  __shared__ double xs[N];
  __shared__ double rr[256];
  double* A   = (double*)((char*)wsv + A_BYTE);
  float*  w0f = (float*)((char*)wsv + W0_BYTE);
  const int tid = threadIdx.x;
  if (tid == 0) xs[256] = A[256 * AP + 257] / A[256 * AP + 256];
  __syncthreads();
  const double x256 = xs[256];
  rr[tid] = A[tid * AP + 257] - A[tid * AP + 256] * x256;
  __syncthreads();
  const int fk0 = tid & ~31;
  const int fs  = tid & 31;
  for (int j = 31; j >= 0; --j) {
    if (fs == j) xs[fk0 + j] = rr[fk0 + j] / A[(fk0 + j) * AP + (fk0 + j)];
    __syncthreads();
    if (fs < j) rr[fk0 + fs] -= A[(fk0 + fs) * AP + (fk0 + j)] * xs[fk0 + j];
    __syncthreads();
  }
  w0f[tid] = (float)xs[tid];
  if (tid == 0) w0f[256] = (float)xs[256];
}

// ---------------------------------------------------------------------------
// combine: out[(b,l), i] = sum_d S[i,d] * W[(b,l), d]
// ---------------------------------------------------------------------------
#define NL 8
__global__ __launch_bounds__(320) void combine_kernel(const float* __restrict__ S,
                                                      const float* __restrict__ om,
                                                      const void* __restrict__ wsv,
                                                      float* __restrict__ out) {
  const int tid = threadIdx.x;
  const int b  = blockIdx.y;
  const int l0 = blockIdx.x * NL;
  const float* w0  = (const float*)((const char*)wsv + W0_BYTE);
  const float* cxy = (const float*)((const char*)wsv + CXY_BYTE);
  __shared__ float Wl[NL][N];
  __shared__ float omsh[2 * MM];
  __shared__ float cxs[NL], cys[NL];

  for (int idx = tid; idx < 2 * MM; idx += 320) omsh[idx] = om[idx];
  if (tid < NL) {
    cxs[tid] = cxy[((size_t)(b * LL) + l0 + tid) * 2];
    cys[tid] = cxy[((size_t)(b * LL) + l0 + tid) * 2 + 1];
  }
  __syncthreads();

  for (int idx = tid; idx < NL * N; idx += 320) {
    const int r = idx / N;
    const int d = idx - r * N;
    float v;
    if (d == 0) {
      v = w0[0];
    } else {
      const int m = (d - 1) >> 1;
      const int pq = 2 * m + 1;
      const float t = cxs[r] * omsh[2 * m] + cys[r] * omsh[2 * m + 1];
      float s, c;
      sincosf(t, &s, &c);
      const float a0 = w0[pq], a1 = w0[pq + 1];
      v = (d & 1) ? (c * a0 - s * a1) : (s * a0 + c * a1);
    }
    Wl[r][d] = v;
  }
  __syncthreads();

  const int i = tid;
  if (i < N) {
    const float* Si = S + (size_t)i * N;
    float acc[NL];
    #pragma unroll
    for (int r = 0; r < NL; ++r) acc[r] = 0.0f;
    #pragma unroll 4
    for (int d = 0; d < N; ++d) {
      const float sv = Si[d];
      #pragma unroll
      for (int r = 0; r < NL; ++r) acc[r] += sv * Wl[r][d];
    }
    const size_t base = (size_t)(b * LL + l0) * N + i;
    #pragma unroll
    for (int r = 0; r < NL; ++r) out[base + (size_t)r * N] = acc[r];
    if (l0 + NL == LL) {
      out[(size_t)BB * LL * N + (size_t)b * N + i] = acc[NL - 1];
    }
  }
}

extern "C" void kernel_launch(void* const* d_in, const int* in_sizes, int n_in,
                              void* d_out, int out_size, void* d_ws, size_t ws_size,
                              hipStream_t stream) {
  const float* x  = (const float*)d_in[0];   // (B, L, 2)
  const float* z0 = (const float*)d_in[1];   // (D,)
  const float* om = (const float*)d_in[2];   // (M, 2)
  const float* S  = (const float*)d_in[3];   // (D, D)
  float* out = (float*)d_out;                // outputs (B,L,D) then z_final (B,D)

  hipLaunchKernelGGL(scan_kernel,  dim3(1),   dim3(512), 0, stream, x, d_ws);
  hipLaunchKernelGGL(stage_kernel, dim3(260), dim3(256), 0, stream, S, z0, d_ws);
  for (int p = 0; p < 8; ++p) {
    const int k0  = p * NB;
    const int tc2 = 258 - (k0 + NB);
    hipLaunchKernelGGL(diag_kernel, dim3(1), dim3(256), 0, stream, d_ws, k0);
    hipLaunchKernelGGL(panel_update_kernel, dim3(8, (tc2 + 63) / 64), dim3(256),
                       0, stream, d_ws, k0, tc2);
  }
  hipLaunchKernelGGL(finish_kernel, dim3(1), dim3(256), 0, stream, d_ws);
  hipLaunchKernelGGL(combine_kernel, dim3(LL / NL, BB), dim3(320), 0, stream, S, om, d_ws, out);
}

// Round 9
// 552.091 us; speedup vs baseline: 1.5198x; 1.5198x over previous
//
#include <hip/hip_runtime.h>
#include <math.h>

#define N    257     // state dim
#define AP   258     // doubles per A row (cols 0..256 = S, col 257 = rhs)
#define MM   128     // rotation pairs
#define LL   512     // seq length
#define BB   4       // batch
#define NB   32      // panel width

// ws byte layout:
#define A_BYTE    0         // double[257*258] = 530448
#define W0_BYTE   530448    // float[257]
#define CXY_BYTE  531488    // float[4096]
#define U12_BYTE  613696    // double[32*226] = 57856 -> ends 671552
#define BINV_BYTE 671552    // double[32*32]  = 8192  -> ends 679744

// ---------------------------------------------------------------------------
// prefix sums of x[b,:,comp]: theta[b,l,m] = cx[b,l]*om0[m] + cy[b,l]*om1[m]
// ---------------------------------------------------------------------------
__global__ __launch_bounds__(512) void scan_kernel(const float* __restrict__ x,
                                                   void* __restrict__ wsv) {
  const int tid  = threadIdx.x;
  const int wave = tid >> 6, lane = tid & 63;
  const int b    = wave >> 1, comp = wave & 1;

  const float* xp = x + ((size_t)b * LL) * 2 + comp;
  double loc[8];
  double run = 0.0;
  #pragma unroll
  for (int e = 0; e < 8; ++e) {
    run += (double)xp[(lane * 8 + e) * 2];
    loc[e] = run;
  }
  double tot = run;
  #pragma unroll
  for (int off = 1; off < 64; off <<= 1) {
    const double o = __shfl_up(tot, off);
    if (lane >= off) tot += o;
  }
  const double excl = tot - run;
  float* cp = (float*)((char*)wsv + CXY_BYTE) + ((size_t)b * LL) * 2 + comp;
  #pragma unroll
  for (int e = 0; e < 8; ++e)
    cp[(lane * 8 + e) * 2] = (float)(excl + loc[e]);
}

// ---------------------------------------------------------------------------
// stage A = [S | z0] in fp64, grid-wide
// ---------------------------------------------------------------------------
__global__ __launch_bounds__(256) void stage_kernel(const float* __restrict__ S,
                                                    const float* __restrict__ z0,
                                                    void* __restrict__ wsv) {
  double* A = (double*)((char*)wsv + A_BYTE);
  const int idx = blockIdx.x * 256 + threadIdx.x;
  if (idx < N * N) {
    const int i = idx / N, j = idx - i * N;
    A[i * AP + j] = (double)S[idx];
  } else {
    const int r = idx - N * N;
    if (r < N) A[r * AP + N] = (double)z0[r];
  }
}

// ---------------------------------------------------------------------------
// diag kernel (1 block, 128 thr): Binv = inv(A[k0:k0+32, k0:k0+32]).
//  - 32x32 LU entirely in REGISTERS via shfl inside wave 0 (no LDS in the
//    sequential core; fully unrolled, compile-time register indices).
//  - invL columns on wave 0, invU columns on wave 1 (parallel, no divergence).
//  - Binv = invU * invL with register-cached invU row; write 8 KB to ws.
// ---------------------------------------------------------------------------
__global__ __launch_bounds__(128) void diag_kernel(void* __restrict__ wsv, int k0) {
  __shared__ double Bsh[NB][NB + 1];
  __shared__ double iL [NB][NB + 1];
  __shared__ double iU [NB][NB + 1];
  __shared__ double rd [NB];
  double* A    = (double*)((char*)wsv + A_BYTE);
  double* Binv = (double*)((char*)wsv + BINV_BYTE);
  const int tid = threadIdx.x;

  if (tid < 64) {
    // --- register LU, rows on lanes 0..31 of wave 0 ---
    double r[NB];
    const bool rowok = tid < NB;
    #pragma unroll
    for (int c = 0; c < NB; ++c)
      r[c] = rowok ? A[(k0 + tid) * AP + k0 + c] : 0.0;
    #pragma unroll
    for (int j = 0; j < NB; ++j) {
      const double ujj  = __shfl(r[j], j);
      const double pinv = 1.0 / ujj;
      const double m = r[j] * pinv;
      #pragma unroll
      for (int j2 = j + 1; j2 < NB; ++j2) {
        const double u = __shfl(r[j2], j);
        if (tid > j && rowok) r[j2] -= m * u;
      }
      if (tid > j && rowok) r[j] = m;
    }
    if (rowok) {
      #pragma unroll
      for (int c = 0; c < NB; ++c) Bsh[tid][c] = r[c];
    }
  }
  // zero iL/iU (2048 entries over 128 threads)
  for (int idx = tid; idx < NB * NB; idx += 128) {
    iL[idx >> 5][idx & 31] = 0.0;
    iU[idx >> 5][idx & 31] = 0.0;
  }
  __syncthreads();
  if (tid < NB) rd[tid] = 1.0 / Bsh[tid][tid];
  __syncthreads();

  // --- triangular inverses: wave 0 -> invL cols, wave 1 -> invU cols ---
  if (tid < NB) {
    const int e = tid;                  // invL column e (unit lower)
    iL[e][e] = 1.0;
    for (int i = e + 1; i < NB; ++i) {
      double v = 0.0;
      for (int t = e; t < i; ++t) v -= Bsh[i][t] * iL[t][e];
      iL[i][e] = v;
    }
  } else if (tid >= 64 && tid < 64 + NB) {
    const int e = tid - 64;             // invU column e
    iU[e][e] = rd[e];
    for (int i = e - 1; i >= 0; --i) {
      double v = 0.0;
      for (int t = i + 1; t <= e; ++t) v -= Bsh[i][t] * iU[t][e];
      iU[i][e] = v * rd[i];
    }
  }
  __syncthreads();

  // --- Binv = iU * iL : thread -> row i = tid>>2, cols j0..j0+7 ---
  {
    const int i  = tid >> 2;
    const int j0 = (tid & 3) * 8;
    double urow[NB];
    #pragma unroll
    for (int t = 0; t < NB; ++t) urow[t] = iU[i][t];
    #pragma unroll
    for (int jj = 0; jj < 8; ++jj) {
      double acc = 0.0;
      #pragma unroll
      for (int t = 0; t < NB; ++t) acc += urow[t] * iL[t][j0 + jj];
      Binv[i * NB + j0 + jj] = acc;
    }
  }
}

// ---------------------------------------------------------------------------
// pivot update (grid, ceil(tc2/64) blocks): Jordan-normalize pivot rows:
//   W = Binv * A_old[k0:k0+32, ct+slice]  -> A (pivot rows) and compact U12w
// ---------------------------------------------------------------------------
__global__ __launch_bounds__(256) void pivot_update_kernel(void* __restrict__ wsv,
                                                           int k0, int tc2) {
  __shared__ double Bs[NB][NB + 1];
  __shared__ double Ao[NB][65];
  double* A    = (double*)((char*)wsv + A_BYTE);
  double* U12w = (double*)((char*)wsv + U12_BYTE);
  const double* Binv = (const double*)((const char*)wsv + BINV_BYTE);
  const int tid = threadIdx.x;
  const int ct  = k0 + NB;
  const int c0  = blockIdx.x * 64;

  for (int idx = tid; idx < NB * NB; idx += 256)
    Bs[idx >> 5][idx & 31] = Binv[idx];
  for (int idx = tid; idx < NB * 64; idx += 256) {
    const int t = idx >> 6, c = idx & 63;
    Ao[t][c] = (c0 + c < tc2) ? A[(k0 + t) * AP + ct + c0 + c] : 0.0;
  }
  __syncthreads();

  const int i  = tid >> 3;           // output row 0..31
  const int c8 = (tid & 7) * 8;      // output cols c8..c8+7 within slice
  double acc[8];
  #pragma unroll
  for (int e = 0; e < 8; ++e) acc[e] = 0.0;
  #pragma unroll 8
  for (int t = 0; t < NB; ++t) {
    const double bv = Bs[i][t];
    #pragma unroll
    for (int e = 0; e < 8; ++e) acc[e] += bv * Ao[t][c8 + e];
  }
  #pragma unroll
  for (int e = 0; e < 8; ++e) {
    const int c = c0 + c8 + e;
    if (c < tc2) {
      A[(k0 + i) * AP + ct + c] = acc[e];
      U12w[i * 226 + c] = acc[e];
    }
  }
}

// ---------------------------------------------------------------------------
// rank update (grid, 8 x ceil(tc2/64) blocks): non-pivot rows R:
//   A[gr, ct+c] -= sum_t A[gr, k0+t] * U12w[t][c]
// ---------------------------------------------------------------------------
__global__ __launch_bounds__(256) void rank_update_kernel(void* __restrict__ wsv,
                                                          int k0, int tc2) {
  __shared__ double Pl[NB][NB + 1];
  __shared__ __align__(16) double Ul[NB][66];
  double* A = (double*)((char*)wsv + A_BYTE);
  const double* U12w = (const double*)((const char*)wsv + U12_BYTE);
  const int tid = threadIdx.x;
  const int ct  = k0 + NB;
  const int rb0 = blockIdx.x * 32;
  const int c0  = blockIdx.y * 64;

  for (int idx = tid; idx < NB * NB; idx += 256) {
    const int i = idx >> 5, c = idx & 31;
    const int rb = rb0 + i;
    const int gr = (rb < k0) ? rb : rb + NB;
    Pl[i][c] = (rb < 225) ? A[gr * AP + k0 + c] : 0.0;
  }
  for (int idx = tid; idx < NB * 64; idx += 256) {
    const int t = idx >> 6, c = idx & 63;
    Ul[t][c] = (c0 + c < tc2) ? U12w[t * 226 + c0 + c] : 0.0;
  }
  __syncthreads();

  const int tr  = tid >> 4;          // 2 rows: tr*2, tr*2+1
  const int tcx = (tid & 15) * 4;    // 4 cols
  double acc[2][4];
  #pragma unroll
  for (int rr = 0; rr < 2; ++rr) {
    const int rb = rb0 + tr * 2 + rr;
    const int gr = (rb < k0) ? rb : rb + NB;
    #pragma unroll
    for (int c = 0; c < 4; ++c)
      acc[rr][c] = (rb < 225 && (c0 + tcx + c) < tc2)
                 ? A[gr * AP + ct + c0 + tcx + c] : 0.0;
  }
  #pragma unroll
  for (int t = 0; t < NB; ++t) {
    const double p0 = Pl[tr * 2][t], p1 = Pl[tr * 2 + 1][t];
    const double2 u0 = *(const double2*)&Ul[t][tcx];
    const double2 u1 = *(const double2*)&Ul[t][tcx + 2];
    acc[0][0] -= p0 * u0.x; acc[0][1] -= p0 * u0.y;
    acc[0][2] -= p0 * u1.x; acc[0][3] -= p0 * u1.y;
    acc[1][0] -= p1 * u0.x; acc[1][1] -= p1 * u0.y;
    acc[1][2] -= p1 * u1.x; acc[1][3] -= p1 * u1.y;
  }
  #pragma unroll
  for (int rr = 0; rr < 2; ++rr) {
    const int rb = rb0 + tr * 2 + rr;
    const int gr = (rb < k0) ? rb : rb + NB;
    #pragma unroll
    for (int c = 0; c < 4; ++c)
      if (rb < 225 && (c0 + tcx + c) < tc2)
        A[gr * AP + ct + c0 + tcx + c] = acc[rr][c];
  }
}

// ---------------------------------------------------------------------------
// finish: rows 0..255 are Jordan-normalized (unit diagonal) ->
//   x256 = rhs256/A[256][256];  w0[k] = rhs[k] - A[k][256]*x256
// ---------------------------------------------------------------------------
__global__ __launch_bounds__(256) void finish_kernel(void* __restrict__ wsv) {
  __shared__ double xs256;
  double* A   = (double*)((char*)wsv + A_BYTE);
  float*  w0f = (float*)((char*)wsv + W0_BYTE);
  const int tid = threadIdx.x;
  if (tid == 0) xs256 = A[256 * AP + 257] / A[256 * AP + 256];
  __syncthreads();
  const double x256 = xs256;
  w0f[tid] = (float)(A[tid * AP + 257] - A[tid * AP + 256] * x256);
  if (tid == 0) w0f[256] = (float)x256;
}

// ---------------------------------------------------------------------------
// combine: out[(b,l), i] = sum_d S[i,d] * W[(b,l), d]
// ---------------------------------------------------------------------------
#define NL 8
__global__ __launch_bounds__(320) void combine_kernel(const float* __restrict__ S,
                                                      const float* __restrict__ om,
                                                      const void* __restrict__ wsv,
                                                      float* __restrict__ out) {
  const int tid = threadIdx.x;
  const int b  = blockIdx.y;
  const int l0 = blockIdx.x * NL;
  const float* w0  = (const float*)((const char*)wsv + W0_BYTE);
  const float* cxy = (const float*)((const char*)wsv + CXY_BYTE);
  __shared__ float Wl[NL][N];
  __shared__ float omsh[2 * MM];
  __shared__ float cxs[NL], cys[NL];

  for (int idx = tid; idx < 2 * MM; idx += 320) omsh[idx] = om[idx];
  if (tid < NL) {
    cxs[tid] = cxy[((size_t)(b * LL) + l0 + tid) * 2];
    cys[tid] = cxy[((size_t)(b * LL) + l0 + tid) * 2 + 1];
  }
  __syncthreads();

  for (int idx = tid; idx < NL * N; idx += 320) {
    const int r = idx / N;
    const int d = idx - r * N;
    float v;
    if (d == 0) {
      v = w0[0];
    } else {
      const int m = (d - 1) >> 1;
      const int pq = 2 * m + 1;
      const float t = cxs[r] * omsh[2 * m] + cys[r] * omsh[2 * m + 1];
      float s, c;
      sincosf(t, &s, &c);
      const float a0 = w0[pq], a1 = w0[pq + 1];
      v = (d & 1) ? (c * a0 - s * a1) : (s * a0 + c * a1);
    }
    Wl[r][d] = v;
  }
  __syncthreads();

  const int i = tid;
  if (i < N) {
    const float* Si = S + (size_t)i * N;
    float acc[NL];
    #pragma unroll
    for (int r = 0; r < NL; ++r) acc[r] = 0.0f;
    #pragma unroll 4
    for (int d = 0; d < N; ++d) {
      const float sv = Si[d];
      #pragma unroll
      for (int r = 0; r < NL; ++r) acc[r] += sv * Wl[r][d];
    }
    const size_t base = (size_t)(b * LL + l0) * N + i;
    #pragma unroll
    for (int r = 0; r < NL; ++r) out[base + (size_t)r * N] = acc[r];
    if (l0 + NL == LL) {
      out[(size_t)BB * LL * N + (size_t)b * N + i] = acc[NL - 1];
    }
  }
}

extern "C" void kernel_launch(void* const* d_in, const int* in_sizes, int n_in,
                              void* d_out, int out_size, void* d_ws, size_t ws_size,
                              hipStream_t stream) {
  const float* x  = (const float*)d_in[0];   // (B, L, 2)
  const float* z0 = (const float*)d_in[1];   // (D,)
  const float* om = (const float*)d_in[2];   // (M, 2)
  const float* S  = (const float*)d_in[3];   // (D, D)
  float* out = (float*)d_out;                // outputs (B,L,D) then z_final (B,D)

  hipLaunchKernelGGL(scan_kernel,  dim3(1),   dim3(512), 0, stream, x, d_ws);
  hipLaunchKernelGGL(stage_kernel, dim3(260), dim3(256), 0, stream, S, z0, d_ws);
  for (int p = 0; p < 8; ++p) {
    const int k0  = p * NB;
    const int tc2 = 258 - (k0 + NB);
    const int ns  = (tc2 + 63) / 64;
    hipLaunchKernelGGL(diag_kernel,         dim3(1),        dim3(128), 0, stream, d_ws, k0);
    hipLaunchKernelGGL(pivot_update_kernel, dim3(ns),       dim3(256), 0, stream, d_ws, k0, tc2);
    hipLaunchKernelGGL(rank_update_kernel,  dim3(8, ns),    dim3(256), 0, stream, d_ws, k0, tc2);
  }
  hipLaunchKernelGGL(finish_kernel, dim3(1), dim3(256), 0, stream, d_ws);
  hipLaunchKernelGGL(combine_kernel, dim3(LL / NL, BB), dim3(320), 0, stream, S, om, d_ws, out);
}